// Round 9
// baseline (890.234 us; speedup 1.0000x reference)
//
#include <hip/hip_runtime.h>

// R9: dual-tile software pipeline on the R7 baseline.
// R7 (634us): MFMA pipe ~1870cyc + VALU ~3045cyc run SERIALLY per block-step
// (5855cyc) because barriers keep the 2 waves/SIMD in phase. R8 proved the
// register budget is saturated (+8 regs -> 6MB spill, 655us), so overlap must
// come free of registers: TWO independent batch tiles per block (MB 16->32,
// 256 blocks = 1 round). Order [P0A;act0A;P0B;act0B] B1 [P1A;act1A;P1B;act1B]
// with sched_barrier(0) between sections -> one acc set live; waves drift into
// antiphase so MFMA(B) issues under act(A) VALU. LDS: sx deleted (x A-frags
// register-prefetched 1 step ahead from global, 16B/thread, row-end guarded);
// h-tiles x2. Numerics: R7's exact ACT + swizzles (absmax anchor 4.88e-4).

typedef _Float16 half_t;
typedef _Float16 half8 __attribute__((ext_vector_type(8)));
typedef _Float16 half4 __attribute__((ext_vector_type(4)));
typedef float f32x4 __attribute__((ext_vector_type(4)));

#define SEQ 100
#define FUT 30
#define TOT (SEQ + FUT)
#define NIN 15
#define MB  16      // rows per tile; 2 tiles per block
#define L2E 1.44269504f

#define MFMA32(A, B, C) __builtin_amdgcn_mfma_f32_16x16x32_f16((A), (B), (C), 0, 0, 0)
#define MFMA16(A, B, C) __builtin_amdgcn_mfma_f32_16x16x16f16((A), (B), (C), 0, 0, 0)

// ---- prep: fp16 repack, gate scales folded (i,f,o: -log2e ; cell g: +2log2e).
// n' = 64*wave + 16*gate + unit%16, unit j = 16*wave + (n&15), row = g*128 + j.
// ws halfword layout:
//   [0,      65536)  WH0[n*128+k]
//   [65536, 131072)  WI1[n*128+k]
//   [131072,196608)  WH1[n*128+k]
//   [196608,204800)  WX [n*16+k]   (k>=15 zero)
//   [204800,206848)  BV: 1024 f32 = scaled (b_ih+b_hh), layer0 then layer1
__global__ void prep_kernel(const float* __restrict__ w_ih0, const float* __restrict__ w_hh0,
                            const float* __restrict__ b_ih0, const float* __restrict__ b_hh0,
                            const float* __restrict__ w_ih1, const float* __restrict__ w_hh1,
                            const float* __restrict__ b_ih1, const float* __restrict__ b_hh1,
                            half_t* __restrict__ wsh)
{
  int idx = blockIdx.x * 256 + threadIdx.x;
  if (idx < 196608) {
    int seg = idx >> 16;
    int r   = idx & 65535;
    int n   = r >> 7, k = r & 127;
    int g   = (n >> 4) & 3;
    int row = g * 128 + ((n >> 6) << 4) + (n & 15);
    float sc = (g == 2) ? (2.0f * L2E) : (-L2E);
    const float* src = (seg == 0) ? w_hh0 : ((seg == 1) ? w_ih1 : w_hh1);
    wsh[idx] = (half_t)(src[row * 128 + k] * sc);
  } else if (idx < 204800) {
    int r   = idx - 196608;
    int n   = r >> 4, k = r & 15;
    int g   = (n >> 4) & 3;
    int row = g * 128 + ((n >> 6) << 4) + (n & 15);
    float sc = (g == 2) ? (2.0f * L2E) : (-L2E);
    wsh[idx] = (half_t)((k < NIN) ? (w_ih0[row * NIN + k] * sc) : 0.0f);
  } else if (idx < 205824) {
    int r     = idx - 204800;
    float* bv = (float*)(wsh + 204800);
    int which = r >> 9, n = r & 511;
    int g     = (n >> 4) & 3;
    int row   = g * 128 + ((n >> 6) << 4) + (n & 15);
    float sc  = (g == 2) ? (2.0f * L2E) : (-L2E);
    bv[r] = ((which == 0) ? (b_ih0[row] + b_hh0[row]) : (b_ih1[row] + b_hh1[row])) * sc;
  }
}

// extract this lane's K16 A-frag from a prefetched float4 (quad3 loads at
// offset 11 to stay in-row; elements are then v.y,v.z,v.w and k=15 pads 0)
__device__ __forceinline__ half4 xfrag(float4 v, int quad) {
  float a = (quad < 3) ? v.x : v.y;
  float b = (quad < 3) ? v.y : v.z;
  float c = (quad < 3) ? v.z : v.w;
  float d = (quad < 3) ? v.w : 0.0f;
  return (half4){(half_t)a, (half_t)b, (half_t)c, (half_t)d};
}

__global__ __launch_bounds__(512, 2)
void lstm_kernel(const float* __restrict__ x,
                 const half_t* __restrict__ wsh,
                 const float* __restrict__ fcw,
                 const float* __restrict__ fcb,
                 float* __restrict__ out)
{
  // h tiles (R7 swizzle): (row m, col k) -> m*128 + (((k>>3) ^ (m&7))<<3) + (k&7)
  __shared__ __align__(16) half_t sh0[2][2][MB * 128];  // [tile][buf] 16 KB
  __shared__ __align__(16) half_t sh1[2][2][MB * 128];  // 16 KB
  __shared__ __align__(16) half_t swx[8192];            // 16 KB
  __shared__ __align__(16) half_t sdec[2][MB * 16];     // [tile][row][16] 1 KB
  __shared__ __align__(16) float  sbias[1024];          // 4 KB
  __shared__ __align__(16) float  sfc[258];

  const half_t* WH0 = wsh;
  const half_t* WI1 = wsh + 65536;
  const half_t* WH1 = wsh + 131072;
  const half_t* WX  = wsh + 196608;
  const float*  BV  = (const float*)(wsh + 204800);

  const int tid   = threadIdx.x;
  const int wave  = tid >> 6;
  const int lane  = tid & 63;
  const int l16   = lane & 15;
  const int quad  = lane >> 4;
  const int nb    = wave * 64;
  const int bbase = blockIdx.x * (2 * MB);

  // ---- persistent B-fragments: recurrent weights (192 regs) ----
  half8 wh0[4][4], wi1[4][4], wh1[4][4];  // [kt][g]
  #pragma unroll
  for (int kt = 0; kt < 4; ++kt) {
    #pragma unroll
    for (int g = 0; g < 4; ++g) {
      int n = nb + g * 16 + l16;
      int k = kt * 32 + quad * 8;
      wh0[kt][g] = *(const half8*)&WH0[n * 128 + k];
      wi1[kt][g] = *(const half8*)&WI1[n * 128 + k];
      wh1[kt][g] = *(const half8*)&WH1[n * 128 + k];
    }
  }

  // ---- one-time LDS staging ----
  for (int it = tid; it < 8192; it += 512) swx[it] = WX[it];
  for (int it = tid; it < 1024; it += 512) sbias[it] = BV[it];
  if (tid < 256) sfc[tid] = fcw[tid];
  if (tid < 2)   sfc[256 + tid] = fcb[tid];
  {
    int b = tid >> 4, i = tid & 15;   // 512 threads = 32 rows x 16
    float v = (i < NIN) ? x[(size_t)(bbase + b) * (SEQ * NIN) + 99 * NIN + i] : 0.f;
    sdec[b >> 4][(b & 15) * 16 + i] = (half_t)v;
  }
  for (int it = tid; it < MB * 128; it += 512) {
    sh0[0][0][it] = (half_t)0; sh0[0][1][it] = (half_t)0;
    sh0[1][0][it] = (half_t)0; sh0[1][1][it] = (half_t)0;
    sh1[0][0][it] = (half_t)0; sh1[0][1][it] = (half_t)0;
    sh1[1][0][it] = (half_t)0; sh1[1][1][it] = (half_t)0;
  }
  __syncthreads();

  float c0A[4] = {0.f, 0.f, 0.f, 0.f}, c0B[4] = {0.f, 0.f, 0.f, 0.f};
  float c1A[4] = {0.f, 0.f, 0.f, 0.f}, c1B[4] = {0.f, 0.f, 0.f, 0.f};
  const int chunk = wave * 2 + (l16 >> 3);

  // fused activation (R7-exact; absmax anchor 4.88e-4):
  // A=2^-xi' C=2^-xf' B=2^+2xg' D=2^-xo' (scales pre-folded in weights/bias)
  // c' = [c*(1+A)(1+B) + (B-1)(1+C)] / [(1+A)(1+B)(1+C)]
  // h  = (E-1) / [(1+D)(1+E)],  E = 2^(2*log2e*c')
  #define ACT_STORE(ACC, CS, DST)                                              \
    _Pragma("unroll")                                                          \
    for (int r = 0; r < 4; ++r) {                                              \
      float A  = __builtin_amdgcn_exp2f((ACC)[0][r]);                          \
      float C  = __builtin_amdgcn_exp2f((ACC)[1][r]);                          \
      float B  = __builtin_amdgcn_exp2f((ACC)[2][r]);                          \
      float D  = __builtin_amdgcn_exp2f((ACC)[3][r]);                          \
      float oA = 1.f + A, oB = 1.f + B, oC = 1.f + C, oD = 1.f + D;            \
      float P  = oA * oB;                                                      \
      float t  = (B - 1.f) * oC;                                               \
      float nm = fmaf((CS)[r], P, t);                                          \
      float rc = __builtin_amdgcn_rcpf(P * oC);                                \
      float cn = nm * rc;                                                      \
      (CS)[r] = cn;                                                            \
      float E  = __builtin_amdgcn_exp2f(2.0f * L2E * cn);                      \
      float h  = (E - 1.f) * __builtin_amdgcn_rcpf(oD * (1.f + E));            \
      int   m  = quad * 4 + r;                                                 \
      (DST)[m * 128 + ((chunk ^ (m & 7)) << 3) + (l16 & 7)] = (half_t)h;       \
    }

  #define P0_SEC(T, AX, CS)                                                    \
    {                                                                          \
      f32x4 acc[4];                                                            \
      _Pragma("unroll")                                                        \
      for (int g = 0; g < 4; ++g) {                                            \
        float b = sbias[nb + g * 16 + l16];                                    \
        acc[g] = (f32x4){b, b, b, b};                                          \
      }                                                                        \
      _Pragma("unroll")                                                        \
      for (int kt = 0; kt < 4; ++kt) {                                         \
        int c = kt * 4 + quad;                                                 \
        half8 ah = *(const half8*)&sh0[T][cur][l16 * 128 + ((c ^ (l16 & 7)) << 3)]; \
        _Pragma("unroll")                                                      \
        for (int g = 0; g < 4; ++g) acc[g] = MFMA32(ah, wh0[kt][g], acc[g]);   \
      }                                                                        \
      _Pragma("unroll")                                                        \
      for (int g = 0; g < 4; ++g) {                                            \
        half4 bx = *(const half4*)&swx[(nb + g * 16 + l16) * 16 + quad * 4];   \
        acc[g] = MFMA16((AX), bx, acc[g]);                                     \
      }                                                                        \
      ACT_STORE(acc, CS, (&sh0[T][nxt][0]))                                    \
    }

  #define P1_SEC(T, CS)                                                        \
    {                                                                          \
      f32x4 acc[4];                                                            \
      _Pragma("unroll")                                                        \
      for (int g = 0; g < 4; ++g) {                                            \
        float b = sbias[512 + nb + g * 16 + l16];                              \
        acc[g] = (f32x4){b, b, b, b};                                          \
      }                                                                        \
      _Pragma("unroll")                                                        \
      for (int kt = 0; kt < 4; ++kt) {                                         \
        int c = kt * 4 + quad;                                                 \
        half8 ah = *(const half8*)&sh0[T][nxt][l16 * 128 + ((c ^ (l16 & 7)) << 3)]; \
        _Pragma("unroll")                                                      \
        for (int g = 0; g < 4; ++g) acc[g] = MFMA32(ah, wi1[kt][g], acc[g]);   \
      }                                                                        \
      _Pragma("unroll")                                                        \
      for (int kt = 0; kt < 4; ++kt) {                                         \
        int c = kt * 4 + quad;                                                 \
        half8 ah = *(const half8*)&sh1[T][cur][l16 * 128 + ((c ^ (l16 & 7)) << 3)]; \
        _Pragma("unroll")                                                      \
        for (int g = 0; g < 4; ++g) acc[g] = MFMA32(ah, wh1[kt][g], acc[g]);   \
      }                                                                        \
      ACT_STORE(acc, CS, (&sh1[T][nxt][0]))                                    \
    }

  // ---- x prefetch pointers (A-frag: row l16 of tile, k = quad*4; quad3 at 11) ----
  const int koff = (quad < 3) ? quad * 4 : 11;
  const float* xpA = x + (size_t)(bbase + l16) * (SEQ * NIN) + koff;
  const float* xpB = xpA + (size_t)MB * (SEQ * NIN);
  float4 xfA = *(const float4*)xpA;   // x(0)
  float4 xfB = *(const float4*)xpB;
  xpA += NIN; xpB += NIN;

  int cur = 0;
  for (int s = 0; s < TOT; ++s) {
    const int nxt = cur ^ 1;

    // prefetch x(s+1) into registers (no LDS, no barrier interaction)
    float4 xnA = xfA, xnB = xfB;
    const bool pf = (s + 1 < SEQ);
    if (pf) {
      xnA = *(const float4*)xpA;
      xnB = *(const float4*)xpB;
      xpA += NIN; xpB += NIN;
    }

    half4 axA, axB;
    if (s < SEQ) {
      axA = xfrag(xfA, quad);
      axB = xfrag(xfB, quad);
    } else {
      axA = *(const half4*)&sdec[0][l16 * 16 + quad * 4];
      axB = *(const half4*)&sdec[1][l16 * 16 + quad * 4];
    }

    // ======= layer 0, tiles A then B (sections pinned apart) =======
    P0_SEC(0, axA, c0A)
    __builtin_amdgcn_sched_barrier(0);
    P0_SEC(1, axB, c0B)
    __syncthreads();  // B1 (the only encoder barrier)

    // ======= layer 1, tiles A then B =======
    P1_SEC(0, c1A)
    __builtin_amdgcn_sched_barrier(0);
    P1_SEC(1, c1B)

    // ======= decoder: FC + feedback =======
    if (s >= SEQ) {
      __syncthreads();  // B2d: h1_new visible
      {
        int b   = wave * 4 + (lane >> 4);   // 0..31
        int tl  = b >> 4, row = b & 15;
        int o   = (lane >> 3) & 1;
        int seg = lane & 7;
        float p = 0.f;
        #pragma unroll
        for (int cc = 0; cc < 2; ++cc) {
          int c = seg * 2 + cc;
          half8 hv = *(const half8*)&sh1[tl][nxt][row * 128 + ((c ^ (row & 7)) << 3)];
          f32x4 w0 = *(const f32x4*)&sfc[o * 128 + c * 8];
          f32x4 w1 = *(const f32x4*)&sfc[o * 128 + c * 8 + 4];
          #pragma unroll
          for (int u = 0; u < 4; ++u) p = fmaf((float)hv[u], w0[u], p);
          #pragma unroll
          for (int u = 0; u < 4; ++u) p = fmaf((float)hv[4 + u], w1[u], p);
        }
        p += __shfl_down(p, 4);
        p += __shfl_down(p, 2);
        p += __shfl_down(p, 1);
        if (seg == 0) {
          p += sfc[256 + o];
          out[(size_t)(bbase + b) * (FUT * 2) + (s - SEQ) * 2 + o] = p;
          sdec[tl][row * 16 + o] = (half_t)p;   // feed back into features 0:2
        }
      }
      __syncthreads();  // B3d: sdec feedback visible
    }

    xfA = xnA; xfB = xnB;
    cur = nxt;
  }
}

extern "C" void kernel_launch(void* const* d_in, const int* in_sizes, int n_in,
                              void* d_out, int out_size, void* d_ws, size_t ws_size,
                              hipStream_t stream)
{
  (void)in_sizes; (void)n_in; (void)out_size; (void)ws_size;
  const float* x     = (const float*)d_in[0];
  const float* w_ih0 = (const float*)d_in[1];
  const float* w_hh0 = (const float*)d_in[2];
  const float* b_ih0 = (const float*)d_in[3];
  const float* b_hh0 = (const float*)d_in[4];
  const float* w_ih1 = (const float*)d_in[5];
  const float* w_hh1 = (const float*)d_in[6];
  const float* b_ih1 = (const float*)d_in[7];
  const float* b_hh1 = (const float*)d_in[8];
  const float* fcw   = (const float*)d_in[9];
  const float* fcb   = (const float*)d_in[10];
  float*  out = (float*)d_out;
  half_t* wsh = (half_t*)d_ws;

  prep_kernel<<<(205824 + 255) / 256, 256, 0, stream>>>(
      w_ih0, w_hh0, b_ih0, b_hh0, w_ih1, w_hh1, b_ih1, b_hh1, wsh);
  lstm_kernel<<<8192 / (2 * MB), 512, 0, stream>>>(x, wsh, fcw, fcb, out);
}

// Round 10
// 643.230 us; speedup vs baseline: 1.3840x; 1.3840x over previous
//
#include <hip/hip_runtime.h>

// R10: R5b's rotation pipeline, made spill-free by evicting WH1 to LDS.
// R8/R9 proved the register file is the wall: 192 weight regs + 1 acc set
// saturates; anything more spills (R9: 237MB scratch). Fix: WH1 (64 regs,
// 128KB fp16) moves to LDS in k-block-major [c][n][8] (B-frag ds_read_b128
// lane-contiguous, conflict-free); the freed 64 regs fund the dual-acc
// rotation [mfma1(s); mfma0(s+1); act1(s); act0(s+1)] -> all 56 MFMAs issue
// before the act VALU and drain underneath it. x-array shrinks to an 8-step
// double-buffered chunk (8KB) so swh1 fits: LDS total ~161KB <= 160KiB.
// Canary: WRITE_SIZE (>2MB = spill = retreat).

typedef _Float16 half_t;
typedef _Float16 half8 __attribute__((ext_vector_type(8)));
typedef _Float16 half4 __attribute__((ext_vector_type(4)));
typedef float f32x4 __attribute__((ext_vector_type(4)));

#define SEQ 100
#define FUT 30
#define TOT (SEQ + FUT)
#define NIN 15
#define MB  16
#define CH  8        // x chunk steps
#define L2E 1.44269504f

#define MFMA32(A, B, C) __builtin_amdgcn_mfma_f32_16x16x32_f16((A), (B), (C), 0, 0, 0)
#define MFMA16(A, B, C) __builtin_amdgcn_mfma_f32_16x16x16f16((A), (B), (C), 0, 0, 0)

// ---- prep: fp16 repack, gate scales folded (i,f,o: -log2e ; cell g: +2log2e).
// n' = 64*wave + 16*gate + unit%16, row = g*128 + 16*(n>>6) + (n&15).
// ws halfword layout:
//   [0,      65536)  WH0 [n*128+k]
//   [65536, 131072)  WI1 [n*128+k]
//   [131072,196608)  WH1L[(c*512+n)*8+e]  c=k>>3, e=k&7  (LDS-ready order)
//   [196608,204800)  WX  [n*16+k]   (k>=15 zero)
//   [204800,206848)  BV: 1024 f32 = scaled (b_ih+b_hh), layer0 then layer1
__global__ void prep_kernel(const float* __restrict__ w_ih0, const float* __restrict__ w_hh0,
                            const float* __restrict__ b_ih0, const float* __restrict__ b_hh0,
                            const float* __restrict__ w_ih1, const float* __restrict__ w_hh1,
                            const float* __restrict__ b_ih1, const float* __restrict__ b_hh1,
                            half_t* __restrict__ wsh)
{
  int idx = blockIdx.x * 256 + threadIdx.x;
  if (idx < 131072) {
    int seg = idx >> 16;
    int r   = idx & 65535;
    int n   = r >> 7, k = r & 127;
    int g   = (n >> 4) & 3;
    int row = g * 128 + ((n >> 6) << 4) + (n & 15);
    float sc = (g == 2) ? (2.0f * L2E) : (-L2E);
    const float* src = (seg == 0) ? w_hh0 : w_ih1;
    wsh[idx] = (half_t)(src[row * 128 + k] * sc);
  } else if (idx < 196608) {
    int r   = idx - 131072;
    int c   = r >> 12;
    int rem = r & 4095;
    int n   = rem >> 3, e = rem & 7;
    int k   = c * 8 + e;
    int g   = (n >> 4) & 3;
    int row = g * 128 + ((n >> 6) << 4) + (n & 15);
    float sc = (g == 2) ? (2.0f * L2E) : (-L2E);
    wsh[idx] = (half_t)(w_hh1[row * 128 + k] * sc);
  } else if (idx < 204800) {
    int r   = idx - 196608;
    int n   = r >> 4, k = r & 15;
    int g   = (n >> 4) & 3;
    int row = g * 128 + ((n >> 6) << 4) + (n & 15);
    float sc = (g == 2) ? (2.0f * L2E) : (-L2E);
    wsh[idx] = (half_t)((k < NIN) ? (w_ih0[row * NIN + k] * sc) : 0.0f);
  } else if (idx < 205824) {
    int r     = idx - 204800;
    float* bv = (float*)(wsh + 204800);
    int which = r >> 9, n = r & 511;
    int g     = (n >> 4) & 3;
    int row   = g * 128 + ((n >> 6) << 4) + (n & 15);
    float sc  = (g == 2) ? (2.0f * L2E) : (-L2E);
    bv[r] = ((which == 0) ? (b_ih0[row] + b_hh0[row]) : (b_ih1[row] + b_hh1[row])) * sc;
  }
}

__global__ __launch_bounds__(512, 2)
void lstm_kernel(const float* __restrict__ x,
                 const half_t* __restrict__ wsh,
                 const float* __restrict__ fcw,
                 const float* __restrict__ fcb,
                 float* __restrict__ out)
{
  // h tiles (R7 swizzle): (row m, col k) -> m*128 + (((k>>3) ^ (m&7))<<3) + (k&7)
  __shared__ __align__(16) half_t swh1[65536];          // 131,072 B  WH1 [c][n][8]
  __shared__ __align__(16) half_t sh0[2][MB * 128];     // 8,192 B
  __shared__ __align__(16) half_t sh1[2][MB * 128];     // 8,192 B
  __shared__ __align__(16) half_t sxc[2][CH * 256];     // 8,192 B  x chunks [t][quad][b][4]
  __shared__ __align__(16) half_t sdec[4 * MB * 4];     // 512 B    [quad][b][4]
  __shared__ __align__(16) float  sbias[1024];          // 4,096 B
  __shared__ __align__(16) float  sfc[258];             // 1,032 B   => total ~161.3 KB

  const half_t* WH0 = wsh;
  const half_t* WI1 = wsh + 65536;
  const half_t* WH1L = wsh + 131072;
  const half_t* WX  = wsh + 196608;
  const float*  BV  = (const float*)(wsh + 204800);

  const int tid   = threadIdx.x;
  const int wave  = tid >> 6;
  const int lane  = tid & 63;
  const int l16   = lane & 15;
  const int quad  = lane >> 4;
  const int nb    = wave * 64;
  const int bbase = blockIdx.x * MB;

  // ---- persistent register weights: WH0 + WI1 (128 regs) + WX (8) ----
  half8 wh0[4][4], wi1[4][4];  // [kt][g]
  #pragma unroll
  for (int kt = 0; kt < 4; ++kt) {
    #pragma unroll
    for (int g = 0; g < 4; ++g) {
      int n = nb + g * 16 + l16;
      int k = kt * 32 + quad * 8;
      wh0[kt][g] = *(const half8*)&WH0[n * 128 + k];
      wi1[kt][g] = *(const half8*)&WI1[n * 128 + k];
    }
  }
  half4 wxr[4];
  #pragma unroll
  for (int g = 0; g < 4; ++g)
    wxr[g] = *(const half4*)&WX[(nb + g * 16 + l16) * 16 + quad * 4];

  // ---- one-time LDS staging ----
  for (int it = tid; it < 8192; it += 512)              // WH1 -> LDS (16B copies)
    ((uint4*)swh1)[it] = ((const uint4*)WH1L)[it];
  for (int it = tid; it < 1024; it += 512) sbias[it] = BV[it];
  if (tid < 256) sfc[tid] = fcw[tid];
  if (tid < 2)   sfc[256 + tid] = fcb[tid];
  {
    int b = (tid >> 4) & 15, i = tid & 15;              // 512 thr: 2x redundant ok
    float v = (i < NIN) ? x[(size_t)(bbase + b) * (SEQ * NIN) + 99 * NIN + i] : 0.f;
    sdec[(i >> 2) * 64 + b * 4 + (i & 3)] = (half_t)v;
  }
  // x chunk 0 (steps 0..7)
  {
    int e0 = tid * 4;                 // 4 halfs per thread
    int t  = e0 >> 8;
    int rm = e0 & 255;
    int qd = rm >> 6, b = (rm & 63) >> 2;
    half4 v;
    #pragma unroll
    for (int i = 0; i < 4; ++i) {
      int f = qd * 4 + i;
      v[i] = (f < NIN) ? (half_t)x[(size_t)(bbase + b) * (SEQ * NIN) + t * NIN + f]
                       : (half_t)0;
    }
    *(half4*)&sxc[0][t * 256 + qd * 64 + b * 4] = v;
  }
  for (int it = tid; it < MB * 128; it += 512) {
    sh0[0][it] = (half_t)0; sh0[1][it] = (half_t)0;
    sh1[0][it] = (half_t)0; sh1[1][it] = (half_t)0;
  }
  __syncthreads();

  float c0[4] = {0.f, 0.f, 0.f, 0.f};
  float c1[4] = {0.f, 0.f, 0.f, 0.f};
  const int kc = wave * 2 + (l16 >> 3);

  // fused activation (R7-exact; absmax anchor 4.88e-4)
  #define ACT_STORE(ACC, CS, DST)                                              \
    _Pragma("unroll")                                                          \
    for (int r = 0; r < 4; ++r) {                                              \
      float A  = __builtin_amdgcn_exp2f((ACC)[0][r]);                          \
      float C  = __builtin_amdgcn_exp2f((ACC)[1][r]);                          \
      float B  = __builtin_amdgcn_exp2f((ACC)[2][r]);                          \
      float D  = __builtin_amdgcn_exp2f((ACC)[3][r]);                          \
      float oA = 1.f + A, oB = 1.f + B, oC = 1.f + C, oD = 1.f + D;            \
      float P  = oA * oB;                                                      \
      float t  = (B - 1.f) * oC;                                               \
      float nm = fmaf((CS)[r], P, t);                                          \
      float rc = __builtin_amdgcn_rcpf(P * oC);                                \
      float cn = nm * rc;                                                      \
      (CS)[r] = cn;                                                            \
      float E  = __builtin_amdgcn_exp2f(2.0f * L2E * cn);                      \
      float h  = (E - 1.f) * __builtin_amdgcn_rcpf(oD * (1.f + E));            \
      int   m  = quad * 4 + r;                                                 \
      (DST)[m * 128 + ((kc ^ (m & 7)) << 3) + (l16 & 7)] = (half_t)h;          \
    }

  // ---- preamble: gates0(0) (h0(-1)=0 -> x-part only) -> h0(0) in sh0[1] ----
  {
    f32x4 acc0[4];
    #pragma unroll
    for (int g = 0; g < 4; ++g) {
      float b = sbias[nb + g * 16 + l16];
      acc0[g] = (f32x4){b, b, b, b};
    }
    half4 ax = *(const half4*)&sxc[0][quad * 64 + l16 * 4];
    #pragma unroll
    for (int g = 0; g < 4; ++g) acc0[g] = MFMA16(ax, wxr[g], acc0[g]);
    ACT_STORE(acc0, c0, sh0[1])
  }
  __syncthreads();

  int cur = 0;
  for (int s = 0; s < TOT - 1; ++s) {
    const int nxt = cur ^ 1;

    // ---- x chunk refill (every CH encoder steps; visible many barriers later)
    if (s < SEQ && (s & (CH - 1)) == 0) {
      int q1 = (s >> 3) + 1;
      if (q1 * CH < SEQ) {
        int e0 = tid * 4;
        int t  = e0 >> 8;
        int rm = e0 & 255;
        int qd = rm >> 6, b = (rm & 63) >> 2;
        int j  = q1 * CH + t;
        half4 v;
        #pragma unroll
        for (int i = 0; i < 4; ++i) {
          int f = qd * 4 + i;
          v[i] = (f < NIN && j < SEQ)
                   ? (half_t)x[(size_t)(bbase + b) * (SEQ * NIN) + j * NIN + f]
                   : (half_t)0;
        }
        *(half4*)&sxc[q1 & 1][t * 256 + qd * 64 + b * 4] = v;
      }
    }

    // ---- all MFMAs first: acc1 = gates1(s), acc0 = gates0(s+1) ----
    f32x4 acc1[4], acc0[4];
    #pragma unroll
    for (int g = 0; g < 4; ++g) {
      float b1v = sbias[512 + nb + g * 16 + l16];
      float b0v = sbias[nb + g * 16 + l16];
      acc1[g] = (f32x4){b1v, b1v, b1v, b1v};
      acc0[g] = (f32x4){b0v, b0v, b0v, b0v};
    }
    #pragma unroll
    for (int kt = 0; kt < 4; ++kt) {
      int c  = kt * 4 + quad;
      int sw = ((c ^ (l16 & 7)) << 3);
      half8 a0 = *(const half8*)&sh0[nxt][l16 * 128 + sw];   // h0(s)
      #pragma unroll
      for (int g = 0; g < 4; ++g) acc1[g] = MFMA32(a0, wi1[kt][g], acc1[g]);
      #pragma unroll
      for (int g = 0; g < 4; ++g) acc0[g] = MFMA32(a0, wh0[kt][g], acc0[g]);
      half8 a1 = *(const half8*)&sh1[cur][l16 * 128 + sw];   // h1(s-1)
      #pragma unroll
      for (int g = 0; g < 4; ++g) {
        half8 bw = *(const half8*)&swh1[(c * 512 + nb + g * 16 + l16) * 8];
        acc1[g] = MFMA32(a1, bw, acc1[g]);
      }
    }
    if (s < SEQ) {  // x(s+1): chunk, or initial sdec (=x(99)) at s=99
      half4 ax;
      if (s + 1 < SEQ) {
        int j = s + 1;
        ax = *(const half4*)&sxc[(j >> 3) & 1][(j & (CH - 1)) * 256 + quad * 64 + l16 * 4];
      } else {
        ax = *(const half4*)&sdec[quad * 64 + l16 * 4];
      }
      #pragma unroll
      for (int g = 0; g < 4; ++g) acc0[g] = MFMA16(ax, wxr[g], acc0[g]);
    }

    // ---- act1(s) -> sh1[nxt]; MFMAs drain underneath ----
    ACT_STORE(acc1, c1, sh1[nxt])

    // ---- decoder: FC(s) then late x-part of acc0 ----
    if (s >= SEQ) {
      __syncthreads();  // B2d: h1(s) visible
      if (tid < 256) {
        int b   = wave * 4 + (lane >> 4);
        int o   = (lane >> 3) & 1;
        int seg = lane & 7;
        float p = 0.f;
        #pragma unroll
        for (int cc = 0; cc < 2; ++cc) {
          int c = seg * 2 + cc;
          half8 hv = *(const half8*)&sh1[nxt][b * 128 + ((c ^ (b & 7)) << 3)];
          f32x4 w0 = *(const f32x4*)&sfc[o * 128 + c * 8];
          f32x4 w1 = *(const f32x4*)&sfc[o * 128 + c * 8 + 4];
          #pragma unroll
          for (int u = 0; u < 4; ++u) p = fmaf((float)hv[u], w0[u], p);
          #pragma unroll
          for (int u = 0; u < 4; ++u) p = fmaf((float)hv[4 + u], w1[u], p);
        }
        p += __shfl_down(p, 4);
        p += __shfl_down(p, 2);
        p += __shfl_down(p, 1);
        if (seg == 0) {
          p += sfc[256 + o];
          out[(size_t)(bbase + b) * (FUT * 2) + (s - SEQ) * 2 + o] = p;
          sdec[b * 4 + o] = (half_t)p;      // [quad0][b][o] = features 0:2
        }
      }
      __syncthreads();  // B3d: sdec(s+1) visible
      half4 ax = *(const half4*)&sdec[quad * 64 + l16 * 4];
      #pragma unroll
      for (int g = 0; g < 4; ++g) acc0[g] = MFMA16(ax, wxr[g], acc0[g]);
    }

    // ---- act0(s+1) -> sh0[cur] ----
    ACT_STORE(acc0, c0, sh0[cur])
    __syncthreads();  // B1
    cur = nxt;
  }

  // ---- epilogue: layer1 step 129 + final FC ----
  {
    const int nxt = cur ^ 1;
    f32x4 acc1[4];
    #pragma unroll
    for (int g = 0; g < 4; ++g) {
      float b = sbias[512 + nb + g * 16 + l16];
      acc1[g] = (f32x4){b, b, b, b};
    }
    #pragma unroll
    for (int kt = 0; kt < 4; ++kt) {
      int c  = kt * 4 + quad;
      int sw = ((c ^ (l16 & 7)) << 3);
      half8 a0 = *(const half8*)&sh0[nxt][l16 * 128 + sw];
      #pragma unroll
      for (int g = 0; g < 4; ++g) acc1[g] = MFMA32(a0, wi1[kt][g], acc1[g]);
      half8 a1 = *(const half8*)&sh1[cur][l16 * 128 + sw];
      #pragma unroll
      for (int g = 0; g < 4; ++g) {
        half8 bw = *(const half8*)&swh1[(c * 512 + nb + g * 16 + l16) * 8];
        acc1[g] = MFMA32(a1, bw, acc1[g]);
      }
    }
    ACT_STORE(acc1, c1, sh1[nxt])
    __syncthreads();
    if (tid < 256) {
      int b   = wave * 4 + (lane >> 4);
      int o   = (lane >> 3) & 1;
      int seg = lane & 7;
      float p = 0.f;
      #pragma unroll
      for (int cc = 0; cc < 2; ++cc) {
        int c = seg * 2 + cc;
        half8 hv = *(const half8*)&sh1[nxt][b * 128 + ((c ^ (b & 7)) << 3)];
        f32x4 w0 = *(const f32x4*)&sfc[o * 128 + c * 8];
        f32x4 w1 = *(const f32x4*)&sfc[o * 128 + c * 8 + 4];
        #pragma unroll
        for (int u = 0; u < 4; ++u) p = fmaf((float)hv[u], w0[u], p);
        #pragma unroll
        for (int u = 0; u < 4; ++u) p = fmaf((float)hv[4 + u], w1[u], p);
      }
      p += __shfl_down(p, 4);
      p += __shfl_down(p, 2);
      p += __shfl_down(p, 1);
      if (seg == 0) {
        p += sfc[256 + o];
        out[(size_t)(bbase + b) * (FUT * 2) + (FUT - 1) * 2 + o] = p;
      }
    }
  }
}

extern "C" void kernel_launch(void* const* d_in, const int* in_sizes, int n_in,
                              void* d_out, int out_size, void* d_ws, size_t ws_size,
                              hipStream_t stream)
{
  (void)in_sizes; (void)n_in; (void)out_size; (void)ws_size;
  const float* x     = (const float*)d_in[0];
  const float* w_ih0 = (const float*)d_in[1];
  const float* w_hh0 = (const float*)d_in[2];
  const float* b_ih0 = (const float*)d_in[3];
  const float* b_hh0 = (const float*)d_in[4];
  const float* w_ih1 = (const float*)d_in[5];
  const float* w_hh1 = (const float*)d_in[6];
  const float* b_ih1 = (const float*)d_in[7];
  const float* b_hh1 = (const float*)d_in[8];
  const float* fcw   = (const float*)d_in[9];
  const float* fcb   = (const float*)d_in[10];
  float*  out = (float*)d_out;
  half_t* wsh = (half_t*)d_ws;

  prep_kernel<<<(205824 + 255) / 256, 256, 0, stream>>>(
      w_ih0, w_hh0, b_ih0, b_hh0, w_ih1, w_hh1, b_ih1, b_hh1, wsh);
  lstm_kernel<<<8192 / MB, 512, 0, stream>>>(x, wsh, fcw, fcb, out);
}